// Round 15
// baseline (6867.171 us; speedup 1.0000x reference)
//
#include <hip/hip_runtime.h>

#define B_ 256
#define T_ 1024
#define H_ 64
#define MAGIC_ 0x5EED7A61u

typedef float f32x2 __attribute__((ext_vector_type(2)));
typedef float f32x4 __attribute__((ext_vector_type(4)));

// fast sigmoid/tanh via v_exp_f32 + v_rcp_f32 (validated R2-R14: absmax 0.0)
__device__ __forceinline__ float fast_sigmoid(float x) {
    float e = __builtin_amdgcn_exp2f(-1.4426950408889634f * x);
    return __builtin_amdgcn_rcpf(1.0f + e);
}
__device__ __forceinline__ float fast_tanh(float x) {
    float e = __builtin_amdgcn_exp2f(2.8853900817779268f * x);
    return 1.0f - 2.0f * __builtin_amdgcn_rcpf(1.0f + e);
}

// butterfly add via DPP: 0xB1=xor1, 0x4E=xor2, 0x141=half-mirror(=xor4 after 1,2)
template<int CTRL>
__device__ __forceinline__ float dpp_addf(float v) {
    int vi = __builtin_bit_cast(int, v);
    int sh = __builtin_amdgcn_update_dpp(0, vi, CTRL, 0xF, 0xF, true);
    return v + __builtin_bit_cast(float, sh);
}

// R8-validated: barrier draining LDS only (no vmcnt drain).
__device__ __forceinline__ void block_sync_lds() {
    asm volatile("s_waitcnt lgkmcnt(0)\n\ts_barrier" ::: "memory");
}

__device__ __forceinline__ float hsum4(f32x4 v) { return (v.x + v.y) + (v.z + v.w); }

__device__ __forceinline__ void spin_flag(const unsigned* f) {
    while (__hip_atomic_load(f, __ATOMIC_RELAXED, __HIP_MEMORY_SCOPE_AGENT) != MAGIC_)
        __builtin_amdgcn_s_sleep(2);
}

// ---------------------------------------------------------------------------
// Fused overlap kernel: 512 blocks x 768 threads.
//  blocks 0-255   = PRODUCER: R8/R12 pair01 [L0+L1] -> buf rows (h_L1) via
//                   agent-scope atomic stores; publishes per-8-row chunk flags
//                   (threadfence + barrier + flag store).
//  blocks 256-511 = CONSUMER: R8 triple [L2+L3+L4], flag-gated agent-scope
//                   atomic reads of h_L1; writes h_L4 IN-PLACE to buf (normal
//                   stores; 2+-round read-before-overwrite gap, R8-proven).
// Deadlock-free: producers never wait; consumers only wait on producer flags.
// Single shared pinned wt[4][8] across role branches (R14-proven aliasing).
// ---------------------------------------------------------------------------
__global__ __attribute__((amdgpu_flat_work_group_size(768, 768)))
void lstm_overlap(const float* __restrict__ x,      // [B,T]
                  float* buf,                       // [B,T,64]: h_L1 -> h_L4 in-place
                  unsigned* __restrict__ flags,     // [256][128] chunk flags
                  const float* __restrict__ w_ih0,  // [256]
                  const float* __restrict__ w_ihr,  // [4,256,64]
                  const float* __restrict__ w_hh,   // [5,256,64]
                  const float* __restrict__ b_ih,   // [5,256]
                  const float* __restrict__ b_hh)   // [5,256]
{
    const int brole = blockIdx.x >> 8;    // 0=producer, 1=consumer
    const int b     = blockIdx.x & 255;   // batch row
    const int tid   = threadIdx.x;

    // producer LDS
    __shared__ __align__(16) float xhA[2][80];
    __shared__ __align__(16) float xhB[2][160];
    // consumer LDS
    __shared__ __align__(16) float bufP[2][144];
    __shared__ __align__(16) float bufM[2][144];
    __shared__ __align__(16) float bufZ[2][144];

    f32x4 wt[4][8];   // shared pinned array across role branches (R14 aliasing)

    const long LW = 4L * H_ * H_;
    const long LB = 4L * H_;

    if (brole == 0) {
        // ================= PRODUCER: [L0 + L1] =================
        const float* wA_ih = w_ih0;
        const float* wA_hh = w_hh;
        const float* bA_ih = b_ih;            const float* bA_hh = b_hh;
        const float* wB_ih = w_ihr;
        const float* wB_hh = w_hh + LW;
        const float* bB_ih = b_ih + LB;       const float* bB_hh = b_hh + LB;
        float* hB_out = buf;

        const bool isB = (tid < 512);
        int kc, j;
        float bias0 = 0.f, bias1 = 0.f, bias2 = 0.f, bias3 = 0.f;
        float w00 = 0.f, w01 = 0.f, w02 = 0.f, w03 = 0.f;

        if (isB) {
            kc = tid & 7; j = tid >> 3;
            #pragma unroll
            for (int r = 0; r < 4; ++r) {
                const int row = r * H_ + j;
                const float* base = (kc < 4) ? (wB_ih + row * H_ + kc * 16)
                                             : (wB_hh + row * H_ + (kc - 4) * 16);
                #pragma unroll
                for (int q = 0; q < 4; ++q) wt[r][q] = *(const f32x4*)(base + 4 * q);
            }
            if (kc == 0) {
                bias0 = bB_ih[0*H_+j] + bB_hh[0*H_+j];
                bias1 = bB_ih[1*H_+j] + bB_hh[1*H_+j];
                bias2 = bB_ih[2*H_+j] + bB_hh[2*H_+j];
                bias3 = bB_ih[3*H_+j] + bB_hh[3*H_+j];
            }
        } else {
            const int t2 = tid - 512;
            kc = t2 & 3; j = t2 >> 2;
            #pragma unroll
            for (int r = 0; r < 4; ++r) {
                const int row = r * H_ + j;
                const float* base = wA_hh + row * H_ + kc * 16;
                #pragma unroll
                for (int q = 0; q < 4; ++q) wt[r][q] = *(const f32x4*)(base + 4 * q);
            }
            if (kc == 0) {
                bias0 = bA_ih[0*H_+j] + bA_hh[0*H_+j];
                bias1 = bA_ih[1*H_+j] + bA_hh[1*H_+j];
                bias2 = bA_ih[2*H_+j] + bA_hh[2*H_+j];
                bias3 = bA_ih[3*H_+j] + bA_hh[3*H_+j];
                w00 = wA_ih[0*H_+j]; w01 = wA_ih[1*H_+j];
                w02 = wA_ih[2*H_+j]; w03 = wA_ih[3*H_+j];
            }
        }
        #pragma unroll
        for (int r = 0; r < 4; ++r)
            #pragma unroll
            for (int q = 0; q < 4; ++q)
                asm volatile("" : "+v"(wt[r][q]));

        float c_st = 0.f;
        float xt = (!isB) ? x[(long)b * T_] : 0.f;

        if (isB) {
            if (tid < H_) xhB[1][80 + (tid >> 4) * 20 + (tid & 15)] = 0.f;  // h_B[-1]=0
        } else {
            const int t2 = tid - 512;
            if (t2 < H_) xhA[0][(t2 >> 4) * 20 + (t2 & 15)] = 0.f;          // h_A[-1]=0
        }
        block_sync_lds();

        for (int s = 0; s <= T_; ++s) {
            const int rb = s & 1, wb = rb ^ 1;

            if (isB) {
                if (s >= 1) {
                    const f32x4* xv = (const f32x4*)&xhB[rb][kc * 20];
                    f32x4 h0 = xv[0], h1 = xv[1], h2 = xv[2], h3 = xv[3];
                    f32x4 a0 = {0,0,0,0}, a1 = {0,0,0,0}, a2 = {0,0,0,0}, a3 = {0,0,0,0};
                    a0 = __builtin_elementwise_fma(wt[0][0], h0, a0);
                    a1 = __builtin_elementwise_fma(wt[1][0], h0, a1);
                    a2 = __builtin_elementwise_fma(wt[2][0], h0, a2);
                    a3 = __builtin_elementwise_fma(wt[3][0], h0, a3);
                    a0 = __builtin_elementwise_fma(wt[0][1], h1, a0);
                    a1 = __builtin_elementwise_fma(wt[1][1], h1, a1);
                    a2 = __builtin_elementwise_fma(wt[2][1], h1, a2);
                    a3 = __builtin_elementwise_fma(wt[3][1], h1, a3);
                    a0 = __builtin_elementwise_fma(wt[0][2], h2, a0);
                    a1 = __builtin_elementwise_fma(wt[1][2], h2, a1);
                    a2 = __builtin_elementwise_fma(wt[2][2], h2, a2);
                    a3 = __builtin_elementwise_fma(wt[3][2], h2, a3);
                    a0 = __builtin_elementwise_fma(wt[0][3], h3, a0);
                    a1 = __builtin_elementwise_fma(wt[1][3], h3, a1);
                    a2 = __builtin_elementwise_fma(wt[2][3], h3, a2);
                    a3 = __builtin_elementwise_fma(wt[3][3], h3, a3);
                    float acc0 = hsum4(a0), acc1 = hsum4(a1);
                    float acc2 = hsum4(a2), acc3 = hsum4(a3);
                    acc0 = dpp_addf<0xB1>(acc0); acc1 = dpp_addf<0xB1>(acc1);
                    acc2 = dpp_addf<0xB1>(acc2); acc3 = dpp_addf<0xB1>(acc3);
                    acc0 = dpp_addf<0x4E>(acc0); acc1 = dpp_addf<0x4E>(acc1);
                    acc2 = dpp_addf<0x4E>(acc2); acc3 = dpp_addf<0x4E>(acc3);
                    acc0 = dpp_addf<0x141>(acc0); acc1 = dpp_addf<0x141>(acc1);
                    acc2 = dpp_addf<0x141>(acc2); acc3 = dpp_addf<0x141>(acc3);
                    if (kc == 0) {
                        float i_ = fast_sigmoid(acc0 + bias0);
                        float f_ = fast_sigmoid(acc1 + bias1);
                        float g_ = fast_tanh   (acc2 + bias2);
                        float o_ = fast_sigmoid(acc3 + bias3);
                        c_st = f_ * c_st + i_ * g_;
                        float h = o_ * fast_tanh(c_st);
                        xhB[wb][80 + (j >> 4) * 20 + (j & 15)] = h;
                        // agent-scope store -> visible at device coherence point
                        __hip_atomic_store(&hB_out[((long)b * T_ + (s - 1)) * H_ + j],
                                           h, __ATOMIC_RELAXED, __HIP_MEMORY_SCOPE_AGENT);
                    }
                }
            } else {
                if (s < T_) {
                    float xn = 0.f;
                    if (s + 1 < T_) xn = x[(long)b * T_ + s + 1];   // wave-uniform
                    const f32x4* xv = (const f32x4*)&xhA[rb][kc * 20];
                    f32x4 h0 = xv[0], h1 = xv[1], h2 = xv[2], h3 = xv[3];
                    f32x4 a0 = {0,0,0,0}, a1 = {0,0,0,0}, a2 = {0,0,0,0}, a3 = {0,0,0,0};
                    a0 = __builtin_elementwise_fma(wt[0][0], h0, a0);
                    a1 = __builtin_elementwise_fma(wt[1][0], h0, a1);
                    a2 = __builtin_elementwise_fma(wt[2][0], h0, a2);
                    a3 = __builtin_elementwise_fma(wt[3][0], h0, a3);
                    a0 = __builtin_elementwise_fma(wt[0][1], h1, a0);
                    a1 = __builtin_elementwise_fma(wt[1][1], h1, a1);
                    a2 = __builtin_elementwise_fma(wt[2][1], h1, a2);
                    a3 = __builtin_elementwise_fma(wt[3][1], h1, a3);
                    a0 = __builtin_elementwise_fma(wt[0][2], h2, a0);
                    a1 = __builtin_elementwise_fma(wt[1][2], h2, a1);
                    a2 = __builtin_elementwise_fma(wt[2][2], h2, a2);
                    a3 = __builtin_elementwise_fma(wt[3][2], h2, a3);
                    a0 = __builtin_elementwise_fma(wt[0][3], h3, a0);
                    a1 = __builtin_elementwise_fma(wt[1][3], h3, a1);
                    a2 = __builtin_elementwise_fma(wt[2][3], h3, a2);
                    a3 = __builtin_elementwise_fma(wt[3][3], h3, a3);
                    float acc0 = hsum4(a0), acc1 = hsum4(a1);
                    float acc2 = hsum4(a2), acc3 = hsum4(a3);
                    acc0 = dpp_addf<0xB1>(acc0); acc1 = dpp_addf<0xB1>(acc1);
                    acc2 = dpp_addf<0xB1>(acc2); acc3 = dpp_addf<0xB1>(acc3);
                    acc0 = dpp_addf<0x4E>(acc0); acc1 = dpp_addf<0x4E>(acc1);
                    acc2 = dpp_addf<0x4E>(acc2); acc3 = dpp_addf<0x4E>(acc3);
                    if (kc == 0) {
                        float i_ = fast_sigmoid(acc0 + bias0 + w00 * xt);
                        float f_ = fast_sigmoid(acc1 + bias1 + w01 * xt);
                        float g_ = fast_tanh   (acc2 + bias2 + w02 * xt);
                        float o_ = fast_sigmoid(acc3 + bias3 + w03 * xt);
                        c_st = f_ * c_st + i_ * g_;
                        float h = o_ * fast_tanh(c_st);
                        const int off = (j >> 4) * 20 + (j & 15);
                        xhA[wb][off] = h;
                        xhB[wb][off] = h;                      // feed B's x-slot
                    }
                    xt = xn;
                }
            }
            block_sync_lds();

            // ---- publish chunk flag every 8 produced rows ----
            const int trow = s - 1;
            if (trow >= 0 && (trow & 7) == 7) {
                __threadfence();          // drain + device-scope visibility
                block_sync_lds();
                if (tid == 0)
                    __hip_atomic_store(&flags[b * 128 + (trow >> 3)], MAGIC_,
                                       __ATOMIC_RELAXED, __HIP_MEMORY_SCOPE_AGENT);
            }
        }
    } else {
        // ================= CONSUMER: [L2 + L3 + L4] =================
        const float* xin  = buf;          // h_L1 (flag-gated)
        float*       hout = buf;          // h_L4 in-place
        const float* wP_ih = w_ihr + 1 * LW;  const float* wP_hh = w_hh + 2 * LW;
        const float* bP_ih = b_ih + 2 * LB;   const float* bP_hh = b_hh + 2 * LB;
        const float* wM_ih = w_ihr + 2 * LW;  const float* wM_hh = w_hh + 3 * LW;
        const float* bM_ih = b_ih + 3 * LB;   const float* bM_hh = b_hh + 3 * LB;
        const float* wZ_ih = w_ihr + 3 * LW;  const float* wZ_hh = w_hh + 4 * LW;
        const float* bZ_ih = b_ih + 4 * LB;   const float* bZ_hh = b_hh + 4 * LB;

        const int role = tid >> 8;      // 0=P(L2), 1=M(L3), 2=Z(L4)
        const int loc  = tid & 255;
        const int kc   = loc & 3;       // 32-float chunk of [x|h]
        const int j    = loc >> 2;      // hidden unit

        const float* w_ih = (role == 0) ? wP_ih : (role == 1) ? wM_ih : wZ_ih;
        const float* w_hh2 = (role == 0) ? wP_hh : (role == 1) ? wM_hh : wZ_hh;
        const float* b_ih2 = (role == 0) ? bP_ih : (role == 1) ? bM_ih : bZ_ih;
        const float* b_hh2 = (role == 0) ? bP_hh : (role == 1) ? bM_hh : bZ_hh;
        float (*myBuf)[144] = (role == 0) ? bufP : (role == 1) ? bufM : bufZ;
        float (*dnBuf)[144] = (role == 0) ? bufM : (role == 1) ? bufZ : bufP;

        #pragma unroll
        for (int r = 0; r < 4; ++r) {
            const int row = r * H_ + j;
            const float* base = (kc < 2) ? (w_ih + row * H_ + kc * 32)
                                         : (w_hh2 + row * H_ + (kc - 2) * 32);
            #pragma unroll
            for (int q = 0; q < 8; ++q)
                wt[r][q] = *(const f32x4*)(base + 4 * q);
        }
        #pragma unroll
        for (int r = 0; r < 4; ++r)
            #pragma unroll
            for (int q = 0; q < 8; ++q)
                asm volatile("" : "+v"(wt[r][q]));

        float bias0 = 0.f, bias1 = 0.f, bias2 = 0.f, bias3 = 0.f;
        if (kc == 0) {
            bias0 = b_ih2[0*H_+j] + b_hh2[0*H_+j];
            bias1 = b_ih2[1*H_+j] + b_hh2[1*H_+j];
            bias2 = b_ih2[2*H_+j] + b_hh2[2*H_+j];
            bias3 = b_ih2[3*H_+j] + b_hh2[3*H_+j];
        }
        float c_st = 0.f;

        // ---- wait for chunk 0 (rows 0-7 of h_L1), then init ----
        if (tid == 0) spin_flag(&flags[b * 128]);
        block_sync_lds();

        if (tid < H_) {
            const int u = tid;
            bufP[0][(u >> 5) * 36 + (u & 31)] =
                __hip_atomic_load(&xin[(long)b * T_ * H_ + u],
                                  __ATOMIC_RELAXED, __HIP_MEMORY_SCOPE_AGENT);
            bufP[0][((u >> 5) + 2) * 36 + (u & 31)] = 0.f;
        } else if (tid < 128) {
            const int u = tid - 64;
            bufM[1][((u >> 5) + 2) * 36 + (u & 31)] = 0.f;
        } else if (tid < 192) {
            const int u = tid - 128;
            bufZ[0][((u >> 5) + 2) * 36 + (u & 31)] = 0.f;
        }
        block_sync_lds();

        for (int s = 0; s <= T_ + 1; ++s) {
            // ---- gate: entering a new 8-row chunk of h_L1 ----
            if (((s + 1) & 7) == 0 && (s + 1) < T_) {
                if (tid == 0) spin_flag(&flags[b * 128 + ((s + 1) >> 3)]);
                block_sync_lds();
            }

            const int rb = s & 1, wb = rb ^ 1;
            const bool active = (role == 0) ? (s < T_)
                              : (role == 1) ? (s >= 1 && s <= T_)
                                            : (s >= 2);
            if (active) {
                float xn = 0.f;
                if (role == 0 && kc == 1 && s + 1 < T_)
                    xn = __hip_atomic_load(&xin[((long)b * T_ + s + 1) * H_ + j],
                                           __ATOMIC_RELAXED, __HIP_MEMORY_SCOPE_AGENT);

                const f32x4* xv = (const f32x4*)&myBuf[rb][kc * 36];
                f32x4 a0 = {0,0,0,0}, a1 = {0,0,0,0}, a2 = {0,0,0,0}, a3 = {0,0,0,0};
                #pragma unroll
                for (int q = 0; q < 8; ++q) {
                    f32x4 hq = xv[q];
                    a0 = __builtin_elementwise_fma(wt[0][q], hq, a0);
                    a1 = __builtin_elementwise_fma(wt[1][q], hq, a1);
                    a2 = __builtin_elementwise_fma(wt[2][q], hq, a2);
                    a3 = __builtin_elementwise_fma(wt[3][q], hq, a3);
                }
                float acc0 = hsum4(a0), acc1 = hsum4(a1);
                float acc2 = hsum4(a2), acc3 = hsum4(a3);
                acc0 = dpp_addf<0xB1>(acc0); acc1 = dpp_addf<0xB1>(acc1);
                acc2 = dpp_addf<0xB1>(acc2); acc3 = dpp_addf<0xB1>(acc3);
                acc0 = dpp_addf<0x4E>(acc0); acc1 = dpp_addf<0x4E>(acc1);
                acc2 = dpp_addf<0x4E>(acc2); acc3 = dpp_addf<0x4E>(acc3);

                if (kc == 0) {
                    float i_ = fast_sigmoid(acc0 + bias0);
                    float f_ = fast_sigmoid(acc1 + bias1);
                    float g_ = fast_tanh   (acc2 + bias2);
                    float o_ = fast_sigmoid(acc3 + bias3);
                    c_st = f_ * c_st + i_ * g_;
                    float h = o_ * fast_tanh(c_st);
                    myBuf[wb][((j >> 5) + 2) * 36 + (j & 31)] = h;       // own h
                    if (role < 2)
                        dnBuf[wb][(j >> 5) * 36 + (j & 31)] = h;         // x of above
                    else
                        hout[((long)b * T_ + (s - 2)) * H_ + j] = h;     // h_L4
                }
                if (role == 0 && kc == 1)
                    bufP[wb][(j >> 5) * 36 + (j & 31)] = xn;             // next x row
            }
            block_sync_lds();
        }
    }
}

// MLP head (R3-R14-validated): wave-uniform W1 -> scalar loads. ~25 us.
__global__ __launch_bounds__(256)
void mlp_head_v2(const float* __restrict__ hbuf,
                 const float* __restrict__ W1,
                 const float* __restrict__ b1,
                 const float* __restrict__ W2,
                 const float* __restrict__ b2,
                 float* __restrict__ out)
{
    const long r = (long)blockIdx.x * 256 + threadIdx.x;

    float row[H_];
    const float4* src = (const float4*)(hbuf + r * H_);
    #pragma unroll
    for (int q = 0; q < 16; ++q) {
        float4 v = src[q];
        row[4*q+0] = fmaxf(v.x, 0.f); row[4*q+1] = fmaxf(v.y, 0.f);
        row[4*q+2] = fmaxf(v.z, 0.f); row[4*q+3] = fmaxf(v.w, 0.f);
    }
    #pragma unroll
    for (int q = 0; q < 16; ++q)
        asm volatile("" : "+v"(row[4*q]), "+v"(row[4*q+1]),
                         "+v"(row[4*q+2]), "+v"(row[4*q+3]));

    float acc = b2[0];
    for (int jj = 0; jj < H_; ++jj) {
        const float* wrow = W1 + jj * H_;
        float s0 = 0.f, s1 = 0.f, s2 = 0.f, s3 = 0.f;
        #pragma unroll
        for (int q = 0; q < 16; ++q) {
            s0 += row[4*q+0] * wrow[4*q+0];
            s1 += row[4*q+1] * wrow[4*q+1];
            s2 += row[4*q+2] * wrow[4*q+2];
            s3 += row[4*q+3] * wrow[4*q+3];
        }
        float y = fmaxf(b1[jj] + (s0 + s1) + (s2 + s3), 0.f);
        acc += y * W2[jj];
    }
    out[r] = acc;
}

extern "C" void kernel_launch(void* const* d_in, const int* in_sizes, int n_in,
                              void* d_out, int out_size, void* d_ws, size_t ws_size,
                              hipStream_t stream) {
    const float* x     = (const float*)d_in[0];   // [B,T,1]
    const float* w_ih0 = (const float*)d_in[1];   // [256]
    const float* w_ihr = (const float*)d_in[2];   // [4,256,64]
    const float* w_hh  = (const float*)d_in[3];   // [5,256,64]
    const float* b_ih  = (const float*)d_in[4];   // [5,256]
    const float* b_hh  = (const float*)d_in[5];   // [5,256]
    const float* W1    = (const float*)d_in[6];   // [64,64]
    const float* b1    = (const float*)d_in[7];   // [64]
    const float* W2    = (const float*)d_in[8];   // [64]
    const float* b2    = (const float*)d_in[9];   // [1]
    // d_in[10] = future (0)

    float* out = (float*)d_out;                   // [B,T] = 262144 floats
    float* buf = (float*)d_ws;                    // [B,T,64] fp32 = 64 MB

    // flags live in the tail of d_out (last 128 KiB = 32768 u32). Poison 0xAA
    // and memset-0 both != MAGIC. mlp_head_v2 overwrites the whole region with
    // real outputs afterwards.
    unsigned* flags = (unsigned*)(out + (out_size - 32768));

    // one launch, 512 blocks: producers [L0+L1] + flag-gated consumers [L2+L3+L4].
    lstm_overlap<<<dim3(512), dim3(768), 0, stream>>>(
        x, buf, flags, w_ih0, w_ihr, w_hh, b_ih, b_hh);

    // MLP head after the pipeline completes (kernel boundary = coherence).
    mlp_head_v2<<<dim3((B_ * T_) / 256), dim3(256), 0, stream>>>(
        buf, W1, b1, W2, b2, out);
}

// Round 16
// 1708.145 us; speedup vs baseline: 4.0203x; 4.0203x over previous
//
#include <hip/hip_runtime.h>

#define B_ 256
#define T_ 1024
#define H_ 64

typedef float f32x2 __attribute__((ext_vector_type(2)));
typedef float f32x4 __attribute__((ext_vector_type(4)));

// fast sigmoid/tanh via v_exp_f32 + v_rcp_f32 (validated R2-R15: absmax 0.0)
__device__ __forceinline__ float fast_sigmoid(float x) {
    float e = __builtin_amdgcn_exp2f(-1.4426950408889634f * x);
    return __builtin_amdgcn_rcpf(1.0f + e);
}
__device__ __forceinline__ float fast_tanh(float x) {
    float e = __builtin_amdgcn_exp2f(2.8853900817779268f * x);
    return 1.0f - 2.0f * __builtin_amdgcn_rcpf(1.0f + e);
}

// butterfly add via DPP: 0xB1=xor1, 0x4E=xor2 (NCH=4 -> 2 stages, R8-validated)
template<int CTRL>
__device__ __forceinline__ float dpp_addf(float v) {
    int vi = __builtin_bit_cast(int, v);
    int sh = __builtin_amdgcn_update_dpp(0, vi, CTRL, 0xF, 0xF, true);
    return v + __builtin_bit_cast(float, sh);
}

// R8-validated: barrier draining LDS only (no vmcnt drain).
__device__ __forceinline__ void block_sync_lds() {
    asm volatile("s_waitcnt lgkmcnt(0)\n\ts_barrier" ::: "memory");
}

__device__ __forceinline__ float hsum4(f32x4 v) { return (v.x + v.y) + (v.z + v.w); }

// ---- heavy role building blocks (R8/R12-validated geometry) ----
// thread = (j in [0,64), kc in [0,4)): 4 gate rows {r*64+j} x 32-float chunk
// of [x(0..63) | h(64..127)]; chunk kc at kc*36 floats (conflict-free b128).
__device__ __forceinline__ void load_w_heavy(const float* __restrict__ w_ih,
                                             const float* __restrict__ w_hh,
                                             int j, int kc, f32x4 wt[4][8]) {
    #pragma unroll
    for (int r = 0; r < 4; ++r) {
        const int row = r * H_ + j;
        const float* base = (kc < 2) ? (w_ih + row * H_ + kc * 32)
                                     : (w_hh + row * H_ + (kc - 2) * 32);
        #pragma unroll
        for (int q = 0; q < 8; ++q)
            wt[r][q] = *(const f32x4*)(base + 4 * q);
    }
    #pragma unroll
    for (int r = 0; r < 4; ++r)
        #pragma unroll
        for (int q = 0; q < 8; ++q)
            asm volatile("" : "+v"(wt[r][q]));
}

__device__ __forceinline__ void dot4x32(const float* chunk, const f32x4 wt[4][8],
                                        float acc[4]) {
    const f32x4* xv = (const f32x4*)chunk;
    f32x4 a0 = {0,0,0,0}, a1 = {0,0,0,0}, a2 = {0,0,0,0}, a3 = {0,0,0,0};
    #pragma unroll
    for (int q = 0; q < 8; ++q) {
        f32x4 hq = xv[q];
        a0 = __builtin_elementwise_fma(wt[0][q], hq, a0);
        a1 = __builtin_elementwise_fma(wt[1][q], hq, a1);
        a2 = __builtin_elementwise_fma(wt[2][q], hq, a2);
        a3 = __builtin_elementwise_fma(wt[3][q], hq, a3);
    }
    acc[0] = hsum4(a0); acc[1] = hsum4(a1);
    acc[2] = hsum4(a2); acc[3] = hsum4(a3);
}

// ---------------------------------------------------------------------------
// K1': diagonal TRIPLE [L0+L1+L2]. role 0 = L0 (light: h-only 16-float
// chunks, scalar-x term), roles 1,2 = heavy. L0 t=s, L1 t=s-1, L2 t=s-2.
// h flows role->role through LDS; L2 writes global h_L2.  (R12, 1048 us)
// ---------------------------------------------------------------------------
__global__ __attribute__((amdgpu_flat_work_group_size(768, 768)))
void lstm_tri012(const float* __restrict__ x,      // [B,T]
                 float* __restrict__ hout,         // [B,T,64] = h_L2
                 const float* __restrict__ w_ih0,  // [256]
                 const float* __restrict__ whh0,
                 const float* __restrict__ bih0, const float* __restrict__ bhh0,
                 const float* __restrict__ wih1, const float* __restrict__ whh1,
                 const float* __restrict__ bih1, const float* __restrict__ bhh1,
                 const float* __restrict__ wih2, const float* __restrict__ whh2,
                 const float* __restrict__ bih2, const float* __restrict__ bhh2)
{
    const int b    = blockIdx.x;
    const int tid  = threadIdx.x;
    const int role = tid >> 8;      // 0=L0, 1=L1, 2=L2 (wave-uniform)
    const int loc  = tid & 255;
    const int kc   = loc & 3;
    const int j    = loc >> 2;      // hidden unit

    __shared__ __align__(16) float bufL0[2][80];    // L0 h: 4 chunks x 20
    __shared__ __align__(16) float bufL1[2][144];   // [x|h]: 4 chunks x 36
    __shared__ __align__(16) float bufL2[2][144];

    f32x4 wt[4][8];                 // L0 uses [4][4] portion
    float bias0 = 0.f, bias1 = 0.f, bias2 = 0.f, bias3 = 0.f;
    float w00 = 0.f, w01 = 0.f, w02 = 0.f, w03 = 0.f;

    if (role == 0) {
        #pragma unroll
        for (int r = 0; r < 4; ++r) {
            const int row = r * H_ + j;
            const float* base = whh0 + row * H_ + kc * 16;
            #pragma unroll
            for (int q = 0; q < 4; ++q)
                wt[r][q] = *(const f32x4*)(base + 4 * q);
        }
        #pragma unroll
        for (int r = 0; r < 4; ++r)
            #pragma unroll
            for (int q = 0; q < 4; ++q)
                asm volatile("" : "+v"(wt[r][q]));
        if (kc == 0) {
            bias0 = bih0[0*H_+j] + bhh0[0*H_+j];
            bias1 = bih0[1*H_+j] + bhh0[1*H_+j];
            bias2 = bih0[2*H_+j] + bhh0[2*H_+j];
            bias3 = bih0[3*H_+j] + bhh0[3*H_+j];
            w00 = w_ih0[0*H_+j]; w01 = w_ih0[1*H_+j];
            w02 = w_ih0[2*H_+j]; w03 = w_ih0[3*H_+j];
        }
    } else {
        const float* wih = (role == 1) ? wih1 : wih2;
        const float* whh = (role == 1) ? whh1 : whh2;
        const float* bih = (role == 1) ? bih1 : bih2;
        const float* bhh = (role == 1) ? bhh1 : bhh2;
        load_w_heavy(wih, whh, j, kc, wt);
        if (kc == 0) {
            bias0 = bih[0*H_+j] + bhh[0*H_+j];
            bias1 = bih[1*H_+j] + bhh[1*H_+j];
            bias2 = bih[2*H_+j] + bhh[2*H_+j];
            bias3 = bih[3*H_+j] + bhh[3*H_+j];
        }
    }
    float c_st = 0.f;
    float xt = (role == 0) ? x[(long)b * T_] : 0.f;

    float (*myBuf)[144] = (role == 1) ? bufL1 : bufL2;

    // LDS init: L0 reads parity 0 at s=0; L1 parity 1 at s=1; L2 parity 0 at s=2.
    if (loc < H_) {
        const int u = loc;
        if (role == 0)      bufL0[0][(u >> 4) * 20 + (u & 15)] = 0.f;         // h_L0[-1]
        else if (role == 1) bufL1[1][(2 + (u >> 5)) * 36 + (u & 31)] = 0.f;   // h_L1[-1]
        else                bufL2[0][(2 + (u >> 5)) * 36 + (u & 31)] = 0.f;   // h_L2[-1]
    }
    block_sync_lds();

    for (int s = 0; s <= T_ + 1; ++s) {
        const int rb = s & 1, wb = rb ^ 1;
        const bool active = (role == 0) ? (s < T_)
                          : (role == 1) ? (s >= 1 && s <= T_)
                                        : (s >= 2);
        if (active) {
            if (role == 0) {
                float xn = 0.f;
                if (s + 1 < T_) xn = x[(long)b * T_ + s + 1];   // wave-uniform
                const f32x4* xv = (const f32x4*)&bufL0[rb][kc * 20];
                f32x4 h0 = xv[0], h1 = xv[1], h2 = xv[2], h3 = xv[3];
                f32x4 a0 = {0,0,0,0}, a1 = {0,0,0,0}, a2 = {0,0,0,0}, a3 = {0,0,0,0};
                a0 = __builtin_elementwise_fma(wt[0][0], h0, a0);
                a1 = __builtin_elementwise_fma(wt[1][0], h0, a1);
                a2 = __builtin_elementwise_fma(wt[2][0], h0, a2);
                a3 = __builtin_elementwise_fma(wt[3][0], h0, a3);
                a0 = __builtin_elementwise_fma(wt[0][1], h1, a0);
                a1 = __builtin_elementwise_fma(wt[1][1], h1, a1);
                a2 = __builtin_elementwise_fma(wt[2][1], h1, a2);
                a3 = __builtin_elementwise_fma(wt[3][1], h1, a3);
                a0 = __builtin_elementwise_fma(wt[0][2], h2, a0);
                a1 = __builtin_elementwise_fma(wt[1][2], h2, a1);
                a2 = __builtin_elementwise_fma(wt[2][2], h2, a2);
                a3 = __builtin_elementwise_fma(wt[3][2], h2, a3);
                a0 = __builtin_elementwise_fma(wt[0][3], h3, a0);
                a1 = __builtin_elementwise_fma(wt[1][3], h3, a1);
                a2 = __builtin_elementwise_fma(wt[2][3], h3, a2);
                a3 = __builtin_elementwise_fma(wt[3][3], h3, a3);
                float acc0 = hsum4(a0), acc1 = hsum4(a1);
                float acc2 = hsum4(a2), acc3 = hsum4(a3);
                acc0 = dpp_addf<0xB1>(acc0); acc1 = dpp_addf<0xB1>(acc1);
                acc2 = dpp_addf<0xB1>(acc2); acc3 = dpp_addf<0xB1>(acc3);
                acc0 = dpp_addf<0x4E>(acc0); acc1 = dpp_addf<0x4E>(acc1);
                acc2 = dpp_addf<0x4E>(acc2); acc3 = dpp_addf<0x4E>(acc3);
                if (kc == 0) {
                    float i_ = fast_sigmoid(acc0 + bias0 + w00 * xt);
                    float f_ = fast_sigmoid(acc1 + bias1 + w01 * xt);
                    float g_ = fast_tanh   (acc2 + bias2 + w02 * xt);
                    float o_ = fast_sigmoid(acc3 + bias3 + w03 * xt);
                    c_st = f_ * c_st + i_ * g_;
                    float h = o_ * fast_tanh(c_st);
                    bufL0[wb][(j >> 4) * 20 + (j & 15)] = h;            // own h
                    bufL1[wb][(j >> 5) * 36 + (j & 31)] = h;            // L1's x
                }
                xt = xn;
            } else {
                float acc[4];
                dot4x32(&myBuf[rb][kc * 36], wt, acc);
                acc[0] = dpp_addf<0xB1>(acc[0]); acc[1] = dpp_addf<0xB1>(acc[1]);
                acc[2] = dpp_addf<0xB1>(acc[2]); acc[3] = dpp_addf<0xB1>(acc[3]);
                acc[0] = dpp_addf<0x4E>(acc[0]); acc[1] = dpp_addf<0x4E>(acc[1]);
                acc[2] = dpp_addf<0x4E>(acc[2]); acc[3] = dpp_addf<0x4E>(acc[3]);
                if (kc == 0) {
                    float i_ = fast_sigmoid(acc[0] + bias0);
                    float f_ = fast_sigmoid(acc[1] + bias1);
                    float g_ = fast_tanh   (acc[2] + bias2);
                    float o_ = fast_sigmoid(acc[3] + bias3);
                    c_st = f_ * c_st + i_ * g_;
                    float h = o_ * fast_tanh(c_st);
                    myBuf[wb][(2 + (j >> 5)) * 36 + (j & 31)] = h;      // own h
                    if (role == 1)
                        bufL2[wb][(j >> 5) * 36 + (j & 31)] = h;        // L2's x
                    else
                        hout[((long)b * T_ + (s - 2)) * H_ + j] = h;
                }
            }
        }
        block_sync_lds();
    }
}

// ---------------------------------------------------------------------------
// K2': diagonal PAIR [L3+L4], both heavy roles. L3 t=s (x = h_L2 from global,
// prefetched), L4 t=s-1 (x = h_L3 via LDS). In-place on buf: L3 reads row s+1
// at step s, L4 overwrites row s-1 at step s -> 2-round gap.  (R12, 645 us)
// ---------------------------------------------------------------------------
__global__ __attribute__((amdgpu_flat_work_group_size(512, 512)))
void lstm_pair34(const float* __restrict__ xin,   // [B,T,64] h_L2 (aliases hout)
                 float* __restrict__ hout,        // [B,T,64] h_L4
                 const float* __restrict__ wih3, const float* __restrict__ whh3,
                 const float* __restrict__ bih3, const float* __restrict__ bhh3,
                 const float* __restrict__ wih4, const float* __restrict__ whh4,
                 const float* __restrict__ bih4, const float* __restrict__ bhh4)
{
    const int b    = blockIdx.x;
    const int tid  = threadIdx.x;
    const int role = tid >> 8;      // 0=L3, 1=L4 (wave-uniform)
    const int loc  = tid & 255;
    const int kc   = loc & 3;
    const int j    = loc >> 2;

    __shared__ __align__(16) float bufL3[2][144];
    __shared__ __align__(16) float bufL4[2][144];

    const float* wih = (role == 0) ? wih3 : wih4;
    const float* whh = (role == 0) ? whh3 : whh4;
    const float* bih = (role == 0) ? bih3 : bih4;
    const float* bhh = (role == 0) ? bhh3 : bhh4;
    float (*myBuf)[144] = (role == 0) ? bufL3 : bufL4;

    f32x4 wt[4][8];
    load_w_heavy(wih, whh, j, kc, wt);

    float bias0 = 0.f, bias1 = 0.f, bias2 = 0.f, bias3 = 0.f;
    if (kc == 0) {
        bias0 = bih[0*H_+j] + bhh[0*H_+j];
        bias1 = bih[1*H_+j] + bhh[1*H_+j];
        bias2 = bih[2*H_+j] + bhh[2*H_+j];
        bias3 = bih[3*H_+j] + bhh[3*H_+j];
    }
    float c_st = 0.f;

    // LDS init: L3 reads parity 0 at s=0 (x row 0 + h=0); L4 parity 1 at s=1.
    if (tid < H_) {
        const int u = tid;
        bufL3[0][(u >> 5) * 36 + (u & 31)] = xin[(long)b * T_ * H_ + u];
        bufL3[0][(2 + (u >> 5)) * 36 + (u & 31)] = 0.f;
    } else if (tid < 128) {
        const int u = tid - 64;
        bufL4[1][(2 + (u >> 5)) * 36 + (u & 31)] = 0.f;
    }
    block_sync_lds();

    for (int s = 0; s <= T_; ++s) {
        const int rb = s & 1, wb = rb ^ 1;
        const bool active = (role == 0) ? (s < T_) : (s >= 1);
        if (active) {
            // L3: prefetch next x row (kc==1 lanes, one float each)
            float xn = 0.f;
            if (role == 0 && kc == 1 && s + 1 < T_)
                xn = xin[((long)b * T_ + s + 1) * H_ + j];

            float acc[4];
            dot4x32(&myBuf[rb][kc * 36], wt, acc);
            acc[0] = dpp_addf<0xB1>(acc[0]); acc[1] = dpp_addf<0xB1>(acc[1]);
            acc[2] = dpp_addf<0xB1>(acc[2]); acc[3] = dpp_addf<0xB1>(acc[3]);
            acc[0] = dpp_addf<0x4E>(acc[0]); acc[1] = dpp_addf<0x4E>(acc[1]);
            acc[2] = dpp_addf<0x4E>(acc[2]); acc[3] = dpp_addf<0x4E>(acc[3]);

            if (kc == 0) {
                float i_ = fast_sigmoid(acc[0] + bias0);
                float f_ = fast_sigmoid(acc[1] + bias1);
                float g_ = fast_tanh   (acc[2] + bias2);
                float o_ = fast_sigmoid(acc[3] + bias3);
                c_st = f_ * c_st + i_ * g_;
                float h = o_ * fast_tanh(c_st);
                myBuf[wb][(2 + (j >> 5)) * 36 + (j & 31)] = h;          // own h
                if (role == 0)
                    bufL4[wb][(j >> 5) * 36 + (j & 31)] = h;            // L4's x
                else
                    hout[((long)b * T_ + (s - 1)) * H_ + j] = h;
            }
            if (role == 0 && kc == 1)
                bufL3[wb][(j >> 5) * 36 + (j & 31)] = xn;               // next x row
        }
        block_sync_lds();
    }
}

// MLP head (R3-R15-validated): wave-uniform W1 -> scalar loads. ~25 us.
__global__ __launch_bounds__(256)
void mlp_head_v2(const float* __restrict__ hbuf,
                 const float* __restrict__ W1,
                 const float* __restrict__ b1,
                 const float* __restrict__ W2,
                 const float* __restrict__ b2,
                 float* __restrict__ out)
{
    const long r = (long)blockIdx.x * 256 + threadIdx.x;

    float row[H_];
    const float4* src = (const float4*)(hbuf + r * H_);
    #pragma unroll
    for (int q = 0; q < 16; ++q) {
        float4 v = src[q];
        row[4*q+0] = fmaxf(v.x, 0.f); row[4*q+1] = fmaxf(v.y, 0.f);
        row[4*q+2] = fmaxf(v.z, 0.f); row[4*q+3] = fmaxf(v.w, 0.f);
    }
    #pragma unroll
    for (int q = 0; q < 16; ++q)
        asm volatile("" : "+v"(row[4*q]), "+v"(row[4*q+1]),
                         "+v"(row[4*q+2]), "+v"(row[4*q+3]));

    float acc = b2[0];
    for (int jj = 0; jj < H_; ++jj) {
        const float* wrow = W1 + jj * H_;
        float s0 = 0.f, s1 = 0.f, s2 = 0.f, s3 = 0.f;
        #pragma unroll
        for (int q = 0; q < 16; ++q) {
            s0 += row[4*q+0] * wrow[4*q+0];
            s1 += row[4*q+1] * wrow[4*q+1];
            s2 += row[4*q+2] * wrow[4*q+2];
            s3 += row[4*q+3] * wrow[4*q+3];
        }
        float y = fmaxf(b1[jj] + (s0 + s1) + (s2 + s3), 0.f);
        acc += y * W2[jj];
    }
    out[r] = acc;
}

extern "C" void kernel_launch(void* const* d_in, const int* in_sizes, int n_in,
                              void* d_out, int out_size, void* d_ws, size_t ws_size,
                              hipStream_t stream) {
    const float* x     = (const float*)d_in[0];   // [B,T,1]
    const float* w_ih0 = (const float*)d_in[1];   // [256]
    const float* w_ihr = (const float*)d_in[2];   // [4,256,64]
    const float* w_hh  = (const float*)d_in[3];   // [5,256,64]
    const float* b_ih  = (const float*)d_in[4];   // [5,256]
    const float* b_hh  = (const float*)d_in[5];   // [5,256]
    const float* W1    = (const float*)d_in[6];   // [64,64]
    const float* b1    = (const float*)d_in[7];   // [64]
    const float* W2    = (const float*)d_in[8];   // [64]
    const float* b2    = (const float*)d_in[9];   // [1]
    // d_in[10] = future (0)

    float* out = (float*)d_out;
    float* buf = (float*)d_ws;                    // [B,T,64] fp32 = 64 MB

    const long LW = 4L * H_ * H_;   // 16384 floats per layer weight block
    const long LB = 4L * H_;        // 256 floats per layer bias block

    // K1': [L0+L1+L2] diagonal triple -> buf = h_L2
    lstm_tri012<<<dim3(B_), dim3(768), 0, stream>>>(
        x, buf,
        w_ih0, w_hh + 0 * LW, b_ih + 0 * LB, b_hh + 0 * LB,
        w_ihr + 0 * LW, w_hh + 1 * LW, b_ih + 1 * LB, b_hh + 1 * LB,
        w_ihr + 1 * LW, w_hh + 2 * LW, b_ih + 2 * LB, b_hh + 2 * LB);

    // K2': [L3+L4] diagonal pair, in-place on buf -> buf = h_L4
    lstm_pair34<<<dim3(B_), dim3(512), 0, stream>>>(
        buf, buf,
        w_ihr + 2 * LW, w_hh + 3 * LW, b_ih + 3 * LB, b_hh + 3 * LB,
        w_ihr + 3 * LW, w_hh + 4 * LW, b_ih + 4 * LB, b_hh + 4 * LB);

    mlp_head_v2<<<dim3((B_ * T_) / 256), dim3(256), 0, stream>>>(
        buf, W1, b1, W2, b2, out);
}